// Round 12
// baseline (3994.305 us; speedup 1.0000x reference)
//
#include <hip/hip_runtime.h>

#define TT 512
#define BB 64
#define EE 300
#define HH 1024
#define GG 4096
#define NSLOT 33   // h ring; flag lockstep bounds skew <= ~2, stale L2 evicted

typedef _Float16 f16x8 __attribute__((ext_vector_type(8)));
typedef float f32x4 __attribute__((ext_vector_type(4)));

// Workspace:
//   flags @0, 1 KB                  flags[p]: step counters
//   hbuf  @1024, NSLOT x 131072 B   [slot][kb32][quad4][b64][j8] f16
//   mask  @off_mask, 512*64*4       [t][b]
//   xA    @off_xA, 512*20480*2      [t][kb10][quad][b64][j8] f16

__device__ __forceinline__ float sigmf(float x) {
    return __fdividef(1.0f, 1.0f + __expf(-x));
}
__device__ __forceinline__ float tanhsf(float x) {
    float e = __expf(-2.0f * fabsf(x));
    float r = __fdividef(1.0f - e, 1.0f + e);
    return copysignf(r, x);
}

__global__ void mask_kernel(const int* __restrict__ seq, float* __restrict__ maskf) {
    int idx = blockIdx.x * 256 + threadIdx.x;   // 512*64
    int t = idx >> 6, b = idx & 63;
    maskf[idx] = (seq[b * TT + t] != 0) ? 1.0f : 0.0f;
}

// xA[t][kb][quad][b][j] = f16(emb[seq[b][t]][e]), e = kb*32+quad*8+j (r7 layout)
__global__ __launch_bounds__(256)
void xgather_kernel(const float* __restrict__ emb, const int* __restrict__ seq,
                    _Float16* __restrict__ xA) {
    __shared__ float xrow[64 * 305];
    const int t = blockIdx.x, tid = threadIdx.x;
    const int r = tid >> 2, sub = tid & 3;
    const int row = seq[r * TT + t];
    for (int e = sub; e < EE; e += 4)
        xrow[r * 305 + e] = emb[row * EE + e];
    __syncthreads();
    unsigned int* dst = (unsigned int*)(xA + (size_t)t * 20480);
    for (int idx = tid; idx < 10240; idx += 256) {
        int el = idx << 1;
        int j = el & 7, b = (el >> 3) & 63, quad = (el >> 9) & 3, kb = el >> 11;
        int e = (kb << 5) + (quad << 3) + j;
        union { _Float16 h[2]; unsigned int u; } pk;
        pk.h[0] = (e < EE)     ? (_Float16)xrow[b * 305 + e]     : (_Float16)0.f;
        pk.h[1] = (e + 1 < EE) ? (_Float16)xrow[b * 305 + e + 1] : (_Float16)0.f;
        dst[idx] = pk.u;
    }
}

// Persistent LSTM = r7 structure with its global tail de-barriered.
// 256 WGs x 512 thr (1 WG/CU via ~112KB LDS). All 8 waves: K-split h.R + x.W
// (B-frags from LDS). Waves 0-3 additionally: reduce + gates for unit u=w
// (c/h state in REGISTERS), publish their own 64 f16 directly (1 store/lane),
// private vmcnt(0) ack, then an LDS ds_add_rtn elects the LAST publisher wave
// to set flags[p]. ONE __syncthreads per step (S3, zb parity-double-buffered);
// waves 4-7 run ahead into xW(t+1)+poll while waves 0-3 do the global tail.
__global__ __launch_bounds__(512, 2)
void lstm_kernel(const _Float16* __restrict__ xA, const float* __restrict__ rk,
                 const float* __restrict__ wk, const float* __restrict__ bias,
                 const float* __restrict__ maskf, _Float16* __restrict__ hbuf,
                 unsigned int* __restrict__ flags, float* __restrict__ out) {
    __shared__ _Float16 RbL[16384];  // [kb32][quad][c16][j8] B-frags of R
    __shared__ _Float16 WbL[5120];   // [kb10][quad][c16][j8] B-frags of W
    __shared__ float zb[2][8704];    // parity x [8w x 16c rows][stride 68]
    __shared__ unsigned int cnt;     // publisher election counter
    const int tid = threadIdx.x;
    const int lane = tid & 63;
    const int w = tid >> 6;
    const int p = blockIdx.x;
    const int p4 = p << 2;
    const int cc = lane & 15, quad = lane >> 4;

    // pack R slice (k x 16 cols) into B-fragment order, f16, once
    for (int i = tid; i < 16384; i += 512) {
        int k = i >> 4, c = i & 15;
        float v = rk[k * GG + ((c >> 2) << 10) + p4 + (c & 3)];
        RbL[((k >> 5) << 9) + (((k >> 3) & 3) << 7) + (c << 3) + (k & 7)] = (_Float16)v;
    }
    for (int i = tid; i < 5120; i += 512) {
        int e = i >> 4, c = i & 15;
        float v = (e < EE) ? wk[e * GG + ((c >> 2) << 10) + p4 + (c & 3)] : 0.f;
        WbL[((e >> 5) << 9) + (((e >> 3) & 3) << 7) + (c << 3) + (e & 7)] = (_Float16)v;
    }
    if (tid == 0) cnt = 0u;
    float bb[4], c_st = 0.f, hown = 0.f;   // gates state (waves 0-3), registers
    if (w < 4) {
#pragma unroll
        for (int gt = 0; gt < 4; ++gt)
            bb[gt] = bias[(gt << 10) + p4 + w];
    }
    int slot = 0, nslot = 1;
    const int fidx = (w << 5) + (lane & 31);   // wave w's producers: p in [32w,32w+32)
    // publish element offset for (k = 4p+w, b = lane):
    const size_t pub_off = ((size_t)(p >> 3) << 11) + ((size_t)((p >> 1) & 3) << 9)
                           + ((size_t)lane << 3) + ((size_t)(p & 1) << 2) + (size_t)w;
    const f16x8* RbH = (const f16x8*)RbL;
    const f16x8* WbH = (const f16x8*)WbL;
    __syncthreads();   // staging + cnt init complete

    for (int t = 0; t < TT; ++t) {
        float m = (w < 4) ? maskf[(t << 6) + lane] : 0.f;   // early, off the chain
        f32x4 acc[4];
#pragma unroll
        for (int mt = 0; mt < 4; ++mt) acc[mt] = (f32x4){0.f, 0.f, 0.f, 0.f};

        // ---- x.W: no remote dep, overlaps the flag poll ----
        const f16x8* xA8 = (const f16x8*)(xA + (size_t)t * 20480);
        {
            int kb = w;
            f16x8 bf = WbH[(kb << 6) + (quad << 4) + cc];
#pragma unroll
            for (int mt = 0; mt < 4; ++mt) {
                f16x8 af = xA8[(kb << 8) + (quad << 6) + (mt << 4) + cc];
                acc[mt] = __builtin_amdgcn_mfma_f32_16x16x32_f16(af, bf, acc[mt], 0, 0, 0);
            }
        }
        if (w < 2) {
            int kb = 8 + w;
            f16x8 bf = WbH[(kb << 6) + (quad << 4) + cc];
#pragma unroll
            for (int mt = 0; mt < 4; ++mt) {
                f16x8 af = xA8[(kb << 8) + (quad << 6) + (mt << 4) + cc];
                acc[mt] = __builtin_amdgcn_mfma_f32_16x16x32_f16(af, bf, acc[mt], 0, 0, 0);
            }
        }

        // ---- wait: my 32 producers must have published h^t ----
        if (t > 0) {
            unsigned int tgt = (unsigned int)t;
            while (!__all((int)(__hip_atomic_load(flags + fidx, __ATOMIC_RELAXED,
                                                  __HIP_MEMORY_SCOPE_AGENT) >= tgt)))
                __builtin_amdgcn_s_sleep(1);
        }
        __builtin_amdgcn_sched_barrier(0);   // keep h loads after the wait

        // ---- recurrent h.R: wave w owns kb 4w..4w+3 ----
        const f16x8* hA8 = (const f16x8*)(hbuf + (size_t)slot * 65536);
#pragma unroll
        for (int kc = 0; kc < 4; ++kc) {
            int kb = (w << 2) + kc;
            f16x8 bf = RbH[(kb << 6) + (quad << 4) + cc];
#pragma unroll
            for (int mt = 0; mt < 4; ++mt) {
                f16x8 af = hA8[(kb << 8) + (quad << 6) + (mt << 4) + cc];
                acc[mt] = __builtin_amdgcn_mfma_f32_16x16x32_f16(af, bf, acc[mt], 0, 0, 0);
            }
        }
        // D layout: col c = cc, b = 16*mt + quad*4 + reg
        float* zbP = &zb[t & 1][0];
#pragma unroll
        for (int mt = 0; mt < 4; ++mt)
            *(f32x4*)(zbP + ((w << 4) + cc) * 68 + (mt << 4) + (quad << 2)) = acc[mt];
        __syncthreads();                               // S3: partials(t) ready (ONLY barrier)

        if (w < 4) {
            float z[4];
#pragma unroll
            for (int gt = 0; gt < 4; ++gt) {
                int c = (gt << 2) + w;
                float s = bb[gt];
#pragma unroll
                for (int wp = 0; wp < 8; ++wp) s += zbP[((wp << 4) + c) * 68 + lane];
                z[gt] = s;
            }
            float fi = sigmf(z[0]);
            float ff = sigmf(z[1]);
            float fg = tanhsf(z[2]);
            float fo = sigmf(z[3]);
            float cn = fmaf(ff, c_st, fi * fg);
            cn = fmaf(m, cn - c_st, c_st);             // masked c update
            c_st = cn;
            float hc = fo * tanhsf(cn);
            hown = fmaf(m, hc - hown, hown);           // masked h update (f32 state)
            // ---- direct publish of unit u=w (1 store/lane), private ack ----
            union { _Float16 h; unsigned short u; } cv;
            cv.h = (_Float16)hown;
            __hip_atomic_store((unsigned short*)(hbuf + (size_t)nslot * 65536 + pub_off),
                               cv.u, __ATOMIC_RELAXED, __HIP_MEMORY_SCOPE_AGENT);
            __asm__ volatile("s_waitcnt vmcnt(0)" ::: "memory");  // my stores acked
            // ---- elect last publisher wave to raise the flag ----
            if (lane == 0) {
                unsigned int old = atomicAdd(&cnt, 1u);    // ds_add_rtn, ~50cy
                if (old == (unsigned int)((t << 2) + 3))
                    __hip_atomic_store(flags + p, (unsigned int)(t + 1),
                                       __ATOMIC_RELAXED, __HIP_MEMORY_SCOPE_AGENT);
            }
        }
        slot = nslot;
        nslot = (nslot + 1 == NSLOT) ? 0 : nslot + 1;
    }
    if (w < 4) out[lane * HH + p4 + w] = hown;   // final h
}

extern "C" void kernel_launch(void* const* d_in, const int* in_sizes, int n_in,
                              void* d_out, int out_size, void* d_ws, size_t ws_size,
                              hipStream_t stream) {
    const float* emb  = (const float*)d_in[0];
    const float* wk   = (const float*)d_in[1];
    const float* rk   = (const float*)d_in[2];
    const float* bias = (const float*)d_in[3];
    const int*   seq  = (const int*)d_in[4];
    float* out = (float*)d_out;
    char* ws = (char*)d_ws;

    const size_t off_hbuf = 1024;
    const size_t off_mask = off_hbuf + (size_t)NSLOT * 131072;
    const size_t off_xA   = off_mask + 131072;
    unsigned int* flags = (unsigned int*)ws;
    _Float16* hbuf  = (_Float16*)(ws + off_hbuf);
    float*    maskf = (float*)(ws + off_mask);
    _Float16* xA    = (_Float16*)(ws + off_xA);

    // zero flags + hbuf slot 0 (contiguous prefix); ws re-poisoned each call
    hipMemsetAsync(ws, 0, off_hbuf + 131072, stream);
    mask_kernel<<<128, 256, 0, stream>>>(seq, maskf);
    xgather_kernel<<<TT, 256, 0, stream>>>(emb, seq, xA);
    lstm_kernel<<<256, 512, 0, stream>>>(xA, rk, wk, bias, maskf, hbuf, flags, out);
}